// Round 4
// baseline (211.252 us; speedup 1.0000x reference)
//
#include <hip/hip_runtime.h>

// SmallRNN: B=4096 chains, T=2048 steps, I=1, H=8, O=1, fp32.
// h_t = tanh(x_t*w_ih + W_hh h_{t-1} + b);  out = fc_w . h_T + fc_b
//
// Round 6: R4-verified kernel + 2x wave replication.
// R5 post-mortem: DPP-fused fmac violated the gfx9 DPP hazard (DPP
// instruction reading ANY VGPR -- incl. the fmac accumulator -- written
// <2 wait states earlier). Fusion abandoned; builtins let the compiler
// insert the required wait states (R4 passed).
// Cost model: 108 cyc/step = ~30 VALU issue + ~38 trans-pipe occupancy
// (v_exp+v_rcp, ~16-20cyc each wave64) + ~35 dependency stall. At
// 1 wave/SIMD all three are serialized. Remedy: a second co-resident
// wave per SIMD overlaps its VALU issue with the first wave's trans
// occupancy and stalls (separate pipes, 1 issue/cyc). Chain count is
// fixed -> the extra waves are pure REPLICAS (grid 512; blocks >=256
// recompute the same chains, store suppressed). Predicted wall
// ~= max(2x30, 2x38) ~= 70-80 cyc/step vs 108.
//
// Layout (unchanged, harness-verified): 16 lanes per chain (8 rows x 2
// column-split replicas; lane p holds r[rho], rho=j^(4*(p>=8)); computes
// 4-term partials for rows rho (P1, seeded with xwb) and rho^4 (P2,
// exchanged via row_ror:8)). 256 thr/block = 16 chains.

#define B_TOTAL 4096
#define T_STEPS 2048
#define H 8

template <int CTRL>
__device__ __forceinline__ float dppf(float v) {
    int i = __float_as_int(v);
    i = __builtin_amdgcn_mov_dpp(i, CTRL, 0xF, 0xF, true);
    return __int_as_float(i);
}

__global__ __launch_bounds__(256, 1) void rnn_fused(
    const float* __restrict__ x,      // [4096, 2048]
    const float* __restrict__ w_ih,   // [8,1]
    const float* __restrict__ w_hh,   // [8,8]
    const float* __restrict__ b_ih,   // [8]
    const float* __restrict__ b_hh,   // [8]
    const float* __restrict__ fc_w,   // [1,8]
    const float* __restrict__ fc_b,   // [1]
    float* __restrict__ out)          // [4096,1]
{
    const int tid      = threadIdx.x;
    const int p        = tid & 15;          // position within 16-lane row
    const int j        = p & 7;             // hidden index within replica
    const int rho      = j ^ ((p >> 3) << 2); // rotated row: j ^ 4 for high replica
    const int rep      = blockIdx.x >> 8;   // 0 = real, 1 = latency-hiding replica
    const int chain    = ((blockIdx.x & 255) << 4) + (tid >> 4);
    const int baseLane = tid & 48;          // wave-relative base of this row

    // C = 2*log2(e): exp(2*pre) = exp2(C*pre).
    const float C = 2.885390081777927f;

    // r-state weights (r = 1/(1+exp2(C*pre)), h = 1-2r folded into W,b):
    //   W'[row][col] = -2*C*W[row][col]
    //   bP_row = C*(b_row + rowsum(W[row])),  wihC_row = C*wih_row
    // Lane p covers columns rho^{0..3}:
    //   wA[k] = W'[rho  ][rho^k]   (own row,    seeded with xwb)
    //   wB[k] = W'[rho^4][rho^k]   (partner row, exchanged via ror:8)
    float wA[4], wB[4];
    float rowsum = 0.0f;
#pragma unroll
    for (int i = 0; i < H; ++i) rowsum += w_hh[rho * H + i];
#pragma unroll
    for (int k = 0; k < 4; ++k) {
        wA[k] = -2.0f * C * w_hh[rho * H + (rho ^ k)];
        wB[k] = -2.0f * C * w_hh[(rho ^ 4) * H + (rho ^ k)];
    }
    const float wihC = C * w_ih[rho];
    const float bP   = C * (b_ih[rho] + b_hh[rho] + rowsum);

    const float* xp = x + (size_t)chain * T_STEPS;

    float r = 0.5f;   // h = 1 - 2r = 0 for every row

    // One RNN step: 3 quad_perm gathers (depth 1), two 4-term partial
    // chains, one ror:8 exchange, one add, then exp2 + add + rcp.
    // Builtins only -- compiler inserts the DPP wait states (R5 lesson).
#define STEP(xval)                                          \
    {                                                       \
        float xwb = fmaf((xval), wihC, bP);  /* off-path */ \
        float g1 = dppf<0xB1>(r);    /* r[rho^1] */         \
        float g2 = dppf<0x4E>(r);    /* r[rho^2] */         \
        float g3 = dppf<0x1B>(r);    /* r[rho^3] */         \
        float p2 = wB[0] * r;                               \
        float p1 = fmaf(wA[0], r, xwb);                     \
        p2 = fmaf(wB[1], g1, p2);                           \
        p1 = fmaf(wA[1], g1, p1);                           \
        p2 = fmaf(wB[2], g2, p2);                           \
        p1 = fmaf(wA[2], g2, p1);                           \
        p2 = fmaf(wB[3], g3, p2);                           \
        p1 = fmaf(wA[3], g3, p1);                           \
        float p2x = dppf<0x128>(p2); /* partner's P2 (XOR8) */ \
        float s = p1 + p2x;                                 \
        float e = __builtin_amdgcn_exp2f(s);                \
        r = __builtin_amdgcn_rcpf(1.0f + e);                \
    }

    // 16-step unroll; prefetch the next 16 x-values a full group ahead.
    float4 c0 = *(const float4*)(xp + 0);
    float4 c1v = *(const float4*)(xp + 4);
    float4 c2v = *(const float4*)(xp + 8);
    float4 c3v = *(const float4*)(xp + 12);

    for (int t = 0; t < T_STEPS; t += 16) {
        float4 n0 = c0, n1 = c1v, n2 = c2v, n3 = c3v;
        if (t + 16 < T_STEPS) {
            n0 = *(const float4*)(xp + t + 16);
            n1 = *(const float4*)(xp + t + 20);
            n2 = *(const float4*)(xp + t + 24);
            n3 = *(const float4*)(xp + t + 28);
        }
        STEP(c0.x) STEP(c0.y) STEP(c0.z) STEP(c0.w)
        STEP(c1v.x) STEP(c1v.y) STEP(c1v.z) STEP(c1v.w)
        STEP(c2v.x) STEP(c2v.y) STEP(c2v.z) STEP(c2v.w)
        STEP(c3v.x) STEP(c3v.y) STEP(c3v.z) STEP(c3v.w)
        c0 = n0; c1v = n1; c2v = n2; c3v = n3;
    }
#undef STEP

    // Final h from r-state; lanes p=0..7 hold rows rho=0..7 (low replica).
    // Only the rep==0 copy stores; the rep==1 copy exists purely to
    // co-occupy the SIMD and overlap trans-pipe/stall cycles.
    float h = fmaf(-2.0f, r, 1.0f);
    float g[H];
#pragma unroll
    for (int k = 0; k < H; ++k) g[k] = __shfl(h, baseLane + k);
    if (p == 0 && rep == 0) {
        float o = fc_b[0];
#pragma unroll
        for (int k = 0; k < H; ++k) o = fmaf(fc_w[k], g[k], o);
        out[chain] = o;
    }
}

extern "C" void kernel_launch(void* const* d_in, const int* in_sizes, int n_in,
                              void* d_out, int out_size, void* d_ws, size_t ws_size,
                              hipStream_t stream) {
    const float* x    = (const float*)d_in[0];
    const float* w_ih = (const float*)d_in[1];
    const float* w_hh = (const float*)d_in[2];
    const float* b_ih = (const float*)d_in[3];
    const float* b_hh = (const float*)d_in[4];
    const float* fc_w = (const float*)d_in[5];
    const float* fc_b = (const float*)d_in[6];
    float* out = (float*)d_out;

    dim3 grid((B_TOTAL / 16) * 2); // 512 blocks -> 2 per CU -> 2 waves/SIMD
    dim3 block(256);               // 4 waves -> 1 per SIMD per block
    hipLaunchKernelGGL(rnn_fused, grid, block, 0, stream,
                       x, w_ih, w_hh, b_ih, b_hh, fc_w, fc_b, out);
}

// Round 5
// 160.629 us; speedup vs baseline: 1.3152x; 1.3152x over previous
//
#include <hip/hip_runtime.h>

// SmallRNN: B=4096 chains, T=2048 steps, I=1, H=8, O=1, fp32.
// h_t = tanh(x_t*w_ih + W_hh h_{t-1} + b);  out = fc_w . h_T + fc_b
//
// Round 7: R4 structure + v_pk_fma_f32 packed dot (grid back to 256).
// R6 post-mortem: 2 waves/SIMD replication REGRESSED 92->154 us: the
// SIMD has ONE issue port for all resident waves; trans occupancy is
// not co-issuable. Issue demand per chain-step is the cost; replication
// doubles it. R4 calibration: removing a full-rate VALU op saves ~4
// cyc/step. So: cut ops. The two 4-term partials multiply the SAME
// gathered g_k -> pack them: v_pk_fma_f32 (VOP3P, gfx90a+) does
//   lo = wB[k]*g_k + p2,  hi = wA[k]*g_k + p1
// with g_k broadcast from word0 via op_sel_hi:[1,0,1]. Seeds fold into
// pk#1 via S = (0, xwb). Step: 17 -> 12 ops.
// Hazards: DPP gathers remain BUILTINS (compiler inserts DPP wait
// states; R5 lesson). The one DPP read of the asm-written accumulator
// (row_ror:8 on P.x) is protected by an s_nop 1 asm data-chained on P
// ("+v"), guaranteeing 2 wait states after the inline-asm write that
// LLVM's hazard recognizer may not model.
//
// Layout (R4-verified): 16 lanes/chain, 8 rows x 2 column-split
// replicas; lane p holds r[rho], rho=j^(4*(p>=8)); computes 4-col
// partials for rows rho (P1=hi, xwb seed) and rho^4 (P2=lo), P2
// exchanged via row_ror:8. 256 thr/block = 16 chains, grid 256 ->
// 1024 waves = 1 wave/SIMD.

#define B_TOTAL 4096
#define T_STEPS 2048
#define H 8

typedef float float2v __attribute__((ext_vector_type(2)));

template <int CTRL>
__device__ __forceinline__ float dppf(float v) {
    int i = __float_as_int(v);
    i = __builtin_amdgcn_mov_dpp(i, CTRL, 0xF, 0xF, true);
    return __int_as_float(i);
}

__global__ __launch_bounds__(256, 1) void rnn_fused(
    const float* __restrict__ x,      // [4096, 2048]
    const float* __restrict__ w_ih,   // [8,1]
    const float* __restrict__ w_hh,   // [8,8]
    const float* __restrict__ b_ih,   // [8]
    const float* __restrict__ b_hh,   // [8]
    const float* __restrict__ fc_w,   // [1,8]
    const float* __restrict__ fc_b,   // [1]
    float* __restrict__ out)          // [4096,1]
{
    const int tid      = threadIdx.x;
    const int p        = tid & 15;          // position within 16-lane row
    const int j        = p & 7;             // hidden index within replica
    const int rho      = j ^ ((p >> 3) << 2); // rotated row: j ^ 4 for high replica
    const int chain    = (blockIdx.x << 4) + (tid >> 4);
    const int baseLane = tid & 48;          // wave-relative base of this row

    // C = 2*log2(e): exp(2*pre) = exp2(C*pre).
    const float C = 2.885390081777927f;

    // r-state weights (r = 1/(1+exp2(C*pre)), h = 1-2r folded into W,b):
    //   W'[row][col] = -2*C*W[row][col]
    //   bP_row = C*(b_row + rowsum(W[row])),  wihC_row = C*wih_row
    // Lane p covers columns rho^{0..3}:
    //   pair Wk = (wB[k], wA[k]):
    //     wA[k] = W'[rho  ][rho^k]  (own row -> hi lane, xwb seed)
    //     wB[k] = W'[rho^4][rho^k]  (partner row -> lo lane, ror:8 exch)
    float wA[4], wB[4];
    float rowsum = 0.0f;
#pragma unroll
    for (int i = 0; i < H; ++i) rowsum += w_hh[rho * H + i];
#pragma unroll
    for (int k = 0; k < 4; ++k) {
        wA[k] = -2.0f * C * w_hh[rho * H + (rho ^ k)];
        wB[k] = -2.0f * C * w_hh[(rho ^ 4) * H + (rho ^ k)];
    }
    const float wihC = C * w_ih[rho];
    const float bP   = C * (b_ih[rho] + b_hh[rho] + rowsum);

    const float2v W0 = {wB[0], wA[0]};
    const float2v W1 = {wB[1], wA[1]};
    const float2v W2 = {wB[2], wA[2]};
    const float2v W3 = {wB[3], wA[3]};

    const float* xp = x + (size_t)chain * T_STEPS;

    // Pair-resident state. Only .x of rp/g* is ever read (op_sel_hi
    // broadcasts word0); .y initialized to keep the pair well-defined.
    float2v rp  = {0.5f, 0.0f};   // r: h = 1-2r = 0
    float2v S   = {0.0f, 0.0f};   // seed pair: (0, xwb); .x stays 0 forever
    float2v g1p = {0.0f, 0.0f};
    float2v g2p = {0.0f, 0.0f};
    float2v g3p = {0.0f, 0.0f};

    // One RNN step, 12 instructions:
    //   xwb fma (off-path) | 3 quad_perm gathers (builtin DPP) |
    //   4 v_pk_fma_f32 (packed P2=lo / P1=hi) | s_nop 1 (DPP hazard) |
    //   ror:8 exchange | add | exp2 | add | rcp.
#define STEP(xval)                                                           \
    {                                                                        \
        S.y = fmaf((xval), wihC, bP);        /* off-path seed */             \
        g1p.x = dppf<0xB1>(rp.x);            /* r[rho^1] */                  \
        g2p.x = dppf<0x4E>(rp.x);            /* r[rho^2] */                  \
        g3p.x = dppf<0x1B>(rp.x);            /* r[rho^3] */                  \
        float2v P;                                                           \
        asm volatile("v_pk_fma_f32 %0, %1, %2, %3 op_sel_hi:[1,0,1]"         \
                     : "=v"(P) : "v"(W0), "v"(rp), "v"(S));                  \
        asm volatile("v_pk_fma_f32 %0, %1, %2, %0 op_sel_hi:[1,0,1]"         \
                     : "+v"(P) : "v"(W1), "v"(g1p));                         \
        asm volatile("v_pk_fma_f32 %0, %1, %2, %0 op_sel_hi:[1,0,1]"         \
                     : "+v"(P) : "v"(W2), "v"(g2p));                         \
        asm volatile("v_pk_fma_f32 %0, %1, %2, %0 op_sel_hi:[1,0,1]"         \
                     : "+v"(P) : "v"(W3), "v"(g3p));                         \
        asm volatile("s_nop 1" : "+v"(P));   /* 2 wait states before DPP */  \
        float p2x = dppf<0x128>(P.x);        /* partner's P2 (XOR8) */       \
        float s = P.y + p2x;                                                 \
        float e = __builtin_amdgcn_exp2f(s);                                 \
        rp.x = __builtin_amdgcn_rcpf(1.0f + e);                              \
    }

    // 16-step unroll; prefetch the next 16 x-values a full group ahead.
    float4 c0 = *(const float4*)(xp + 0);
    float4 c1v = *(const float4*)(xp + 4);
    float4 c2v = *(const float4*)(xp + 8);
    float4 c3v = *(const float4*)(xp + 12);

    for (int t = 0; t < T_STEPS; t += 16) {
        float4 n0 = c0, n1 = c1v, n2 = c2v, n3 = c3v;
        if (t + 16 < T_STEPS) {
            n0 = *(const float4*)(xp + t + 16);
            n1 = *(const float4*)(xp + t + 20);
            n2 = *(const float4*)(xp + t + 24);
            n3 = *(const float4*)(xp + t + 28);
        }
        STEP(c0.x) STEP(c0.y) STEP(c0.z) STEP(c0.w)
        STEP(c1v.x) STEP(c1v.y) STEP(c1v.z) STEP(c1v.w)
        STEP(c2v.x) STEP(c2v.y) STEP(c2v.z) STEP(c2v.w)
        STEP(c3v.x) STEP(c3v.y) STEP(c3v.z) STEP(c3v.w)
        c0 = n0; c1v = n1; c2v = n2; c3v = n3;
    }
#undef STEP

    // Final h from r-state; lanes p=0..7 hold rows rho=0..7 (low replica).
    float h = fmaf(-2.0f, rp.x, 1.0f);
    float g[H];
#pragma unroll
    for (int k = 0; k < H; ++k) g[k] = __shfl(h, baseLane + k);
    if (p == 0) {
        float o = fc_b[0];
#pragma unroll
        for (int k = 0; k < H; ++k) o = fmaf(fc_w[k], g[k], o);
        out[chain] = o;
    }
}

extern "C" void kernel_launch(void* const* d_in, const int* in_sizes, int n_in,
                              void* d_out, int out_size, void* d_ws, size_t ws_size,
                              hipStream_t stream) {
    const float* x    = (const float*)d_in[0];
    const float* w_ih = (const float*)d_in[1];
    const float* w_hh = (const float*)d_in[2];
    const float* b_ih = (const float*)d_in[3];
    const float* b_hh = (const float*)d_in[4];
    const float* fc_w = (const float*)d_in[5];
    const float* fc_b = (const float*)d_in[6];
    float* out = (float*)d_out;

    dim3 grid(B_TOTAL / 16);   // 256 blocks -> 1 per CU (R6 replication reverted)
    dim3 block(256);           // 4 waves -> 1 per SIMD
    hipLaunchKernelGGL(rnn_fused, grid, block, 0, stream,
                       x, w_ih, w_hh, b_ih, b_hh, fc_w, fc_b, out);
}